// Round 3
// baseline (627.845 us; speedup 1.0000x reference)
//
#include <hip/hip_runtime.h>
#include <stdint.h>

// MHSA: B=4, S=2048, D=1024, H=16, dk=64. fp32 in/out, bf16 MFMA compute.
//
// Pipeline:
//  k0: cvtAll   fp32 -> bf16 for x + all 4 weights (single launch).
//  k1: gemm<0>  QKV projection; Q pre-scaled by 0.125*log2(e).
//               R9: XCD-aware 1D grid swizzle — each XCD owns 8 m-blocks
//               (2 MB A-slice, L2-resident) and iterates all (n,z) over it;
//               V (z==2) epilogue writes V^T [B,H,dk,S] directly.
//               R10: __launch_bounds__(256,6) — R9 inflated VGPR 76->104
//               (occupancy 27->20%) and regressed 74->81us despite FETCH
//               137->49MB; cap allocator at 85 VGPR to restore 6 blocks/CU.
//  k3: attn4    S^T = K Q^T flash attention; C-init = -4*log2(e);
//               v_perm bf16 pack; XOR-swizzled LDS; double-buffered K/V,
//               one barrier/iter; rowsum via ones-MFMA; O over Q in-place.
//               R8: XCD-aware grid: blockIdx.x = bh (64), blockIdx.y = q-pair
//               (16). linear id = bh + 64*qp => id%8 = bh%8 => all 16 blocks
//               of one head share an XCD/L2 -> K/V re-reads become L2 hits.
//  k4: gemm<1>  output projection, fp32 out. R9 swizzle likewise.

typedef __attribute__((ext_vector_type(8))) short short8;
typedef __attribute__((ext_vector_type(4))) short short4v;
typedef __attribute__((ext_vector_type(4))) float float4v;
typedef __attribute__((ext_vector_type(2))) unsigned int uint2v;

#define QSCALE 0.18033688011112042f  // 0.125 * log2(e), folded into Q
#define EXP_C2 5.770780163555852f    // 4 * log2(e), folded into MFMA C-init

__device__ inline short f2bf(float f) {
  union { float f; uint32_t u; } v; v.f = f;
  uint32_t r = (v.u + 0x7fffu + ((v.u >> 16) & 1)) >> 16;
  return (short)(uint16_t)r;
}

// pack 2 f32 -> 2 bf16 (truncating), a -> low short, b -> high short
__device__ inline unsigned int pack2bf(float a, float b) {
  union { float f; unsigned int u; } ua, ub;
  ua.f = a; ub.f = b;
  return __builtin_amdgcn_perm(ub.u, ua.u, 0x07060302u);
}

__device__ inline void async_copy16(const void* g, void* l) {
  __builtin_amdgcn_global_load_lds(
      (const __attribute__((address_space(1))) void*)g,
      (__attribute__((address_space(3))) void*)l, 16, 0, 0);
}

// ---------------------------------------------------------------------------
// fp32 -> bf16: x (8192 blocks) + 4 weights (1024 blocks each) in one launch.
// ---------------------------------------------------------------------------
__global__ __launch_bounds__(256) void cvtAll(
    const float* __restrict__ x, const float* __restrict__ wq,
    const float* __restrict__ wk, const float* __restrict__ wv,
    const float* __restrict__ wo,
    short* __restrict__ xb, short* __restrict__ wqb, short* __restrict__ wkb,
    short* __restrict__ wvb, short* __restrict__ wob) {
  const int b = blockIdx.x;
  const float* s; short* d; int base;
  if (b < 8192) { s = x; d = xb; base = b; }
  else {
    const int wi = (b - 8192) >> 10; base = (b - 8192) & 1023;
    s = (wi == 0) ? wq : (wi == 1) ? wk : (wi == 2) ? wv : wo;
    d = (wi == 0) ? wqb : (wi == 1) ? wkb : (wi == 2) ? wvb : wob;
  }
  const size_t i = (size_t)base * 256 + threadIdx.x;
  const float4v v = *(const float4v*)(s + 4 * i);
  short4v o;
  o[0] = f2bf(v[0]); o[1] = f2bf(v[1]);
  o[2] = f2bf(v[2]); o[3] = f2bf(v[3]);
  *(short4v*)(d + 4 * i) = o;
}

// ---------------------------------------------------------------------------
// GEMM: Y[8192][1024] = A[8192][1024] @ W^T bf16.
// MODE 0: 1D grid 1536; 3 weights via swizzled z; Y bf16 [B,H,S,dk]
//         (z==0 Q scaled; z==2 V written transposed [B,H,dk,S]).
// MODE 1: 1D grid 512; A read through [B,H,S,dk] map; Y fp32 row-major.
// R9 swizzle: o%8 = XCD. Each XCD gets m-blocks [8k,8k+8) (A slice 2 MB,
// stays L2-resident) and walks (n,z) with m-offset innermost, so the W-tile
// (256 KB) is reused 8x back-to-back while the A slice cycles in L2.
// ---------------------------------------------------------------------------
template <int MODE>
__global__ __launch_bounds__(256, 6) void gemm_bt(
    const short* __restrict__ A,
    const short* __restrict__ W0, const short* __restrict__ W1,
    const short* __restrict__ W2,
    short* __restrict__ Yb0, short* __restrict__ Yb1, short* __restrict__ Yb2,
    float* __restrict__ Yf) {
  constexpr int Kd = 1024;
  __shared__ __align__(16) short As[128 * 32];
  __shared__ __align__(16) short Bs[128 * 32];

  const int t = threadIdx.x;
  const int w = t >> 6, l = t & 63, l15 = l & 15, quad = l >> 4;
  const int wm = w >> 1, wn = w & 1;

  int mblk, nblk, zz = 0;
  {
    const int o = blockIdx.x;
    const int xcd = o & 7, slot = o >> 3;
    mblk = (xcd << 3) | (slot & 7);
    const int c = slot >> 3;
    if (MODE == 0) { nblk = c & 7; zz = c >> 3; }
    else nblk = c;
  }
  const int m0 = mblk * 128, n0 = nblk * 128;

  const short* W = W0;
  short* Yb = Yb0;
  float sc = 1.0f;
  if (MODE == 0) {
    if (zz == 0) sc = QSCALE;
    else if (zz == 1) { W = W1; Yb = Yb1; }
    else { W = W2; Yb = Yb2; }
  }

  float4v acc[4][4];
#pragma unroll
  for (int i = 0; i < 4; i++)
#pragma unroll
    for (int j = 0; j < 4; j++) acc[i][j] = (float4v){0.f, 0.f, 0.f, 0.f};

  const int r4 = t >> 2, c48 = (t & 3) * 8;
  const short* Wbase = W + (n0 + r4) * Kd + c48;
  short* AsW = &As[w * 512];
  short* BsW = &Bs[w * 512];
  const int i0 = m0 + r4;
  const int i1 = m0 + 64 + r4;

  for (int k0 = 0; k0 < Kd; k0 += 32) {
    if (MODE == 0) {
      async_copy16(A + (size_t)i0 * Kd + k0 + c48, AsW);
      async_copy16(A + (size_t)i1 * Kd + k0 + c48, AsW + 2048);
    } else {
      const int k = k0 + c48, h = k >> 6, dd = k & 63;
      async_copy16(A + ((((size_t)(i0 >> 11) * 16 + h) * 2048 + (i0 & 2047)) * 64 + dd), AsW);
      async_copy16(A + ((((size_t)(i1 >> 11) * 16 + h) * 2048 + (i1 & 2047)) * 64 + dd), AsW + 2048);
    }
    async_copy16(Wbase + k0, BsW);
    async_copy16(Wbase + 64 * Kd + k0, BsW + 2048);
    __syncthreads();
    short8 af[4], bf[4];
#pragma unroll
    for (int mi = 0; mi < 4; mi++)
      af[mi] = *(const short8*)&As[(wm * 64 + mi * 16 + l15) * 32 + quad * 8];
#pragma unroll
    for (int ni = 0; ni < 4; ni++)
      bf[ni] = *(const short8*)&Bs[(wn * 64 + ni * 16 + l15) * 32 + quad * 8];
#pragma unroll
    for (int mi = 0; mi < 4; mi++)
#pragma unroll
      for (int ni = 0; ni < 4; ni++)
        acc[mi][ni] = __builtin_amdgcn_mfma_f32_16x16x32_bf16(
            af[mi], bf[ni], acc[mi][ni], 0, 0, 0);
    __syncthreads();
  }

#pragma unroll
  for (int mi = 0; mi < 4; mi++) {
    const int ib = m0 + wm * 64 + mi * 16 + quad * 4;
#pragma unroll
    for (int ni = 0; ni < 4; ni++) {
      const int j = n0 + wn * 64 + ni * 16 + l15;
      if (MODE == 0 && zz == 2) {
        // V^T store: [B,H,dk,S]; rows ib..ib+3 are consecutive s -> short4.
        short4v o;
#pragma unroll
        for (int r = 0; r < 4; r++) o[r] = f2bf(acc[mi][ni][r]);
        *(short4v*)&Yb[(((size_t)(ib >> 11) * 16 + (j >> 6)) * 64 + (j & 63)) * 2048 +
                       (ib & 2047)] = o;
      } else {
#pragma unroll
        for (int r = 0; r < 4; r++) {
          const int i = ib + r;
          if (MODE == 0) {
            Yb[((((size_t)(i >> 11) * 16 + (j >> 6)) * 2048 + (i & 2047)) * 64 + (j & 63))] =
                f2bf(acc[mi][ni][r] * sc);
          } else {
            Yf[(size_t)i * 1024 + j] = acc[mi][ni][r];
          }
        }
      }
    }
  }
}

// ---------------------------------------------------------------------------
// Flash attention v4 + XCD swizzle. grid (64 bh, 16 qp), 256 thr = 4 waves.
// Paired q-tiles (qp, 31-qp). XOR-swizzled LDS rows of 64 shorts.
// Double-buffered K/V, one __syncthreads per 64-key iter.
// ---------------------------------------------------------------------------
__global__ __launch_bounds__(256) void attn4(
    short* __restrict__ Q,          // [B,H,S,dk] in, O out
    const short* __restrict__ K,    // [B,H,S,dk]
    const short* __restrict__ VT) { // [B,H,dk,S]
  __shared__ __align__(16) short Ks[2][64 * 64];
  __shared__ __align__(16) short Vs[2][64 * 64];
  __shared__ __align__(16) short Ps[4][16 * 64];

  const int t = threadIdx.x;
  const int w = t >> 6, l = t & 63, l15 = l & 15, quad = l >> 4;
  const int bh = blockIdx.x;   // R8: bh on x => id%8 = bh%8 => per-head XCD
  const int qp = blockIdx.y;   // q-pair index 0..15
  short* Qh = Q + (size_t)bh * 2048 * 64;
  const short* Kh = K + (size_t)bh * 2048 * 64;
  const short* Vh = VT + (size_t)bh * 64 * 2048;

  // staging: thread t covers row sr (0..63), short-chunks 2c0, 2c0+1
  const int sr = t >> 2, c0 = t & 3;
  const int ssw = sr & 7;
  const int stA = sr * 64 + (((2 * c0) ^ ssw) << 3);
  const int stB = sr * 64 + (((2 * c0 + 1) ^ ssw) << 3);
  const int gA = c0 * 16, gB = c0 * 16 + 8;

  // fragment chunk swizzle key
  const int fsw = l15 & 7;
  const int fc0 = (quad ^ fsw) << 3;
  const int fc1 = ((4 + quad) ^ fsw) << 3;
  short* PsW = &Ps[w][0];
  const int pwr = l15 * 64;

  short8 ones;
#pragma unroll
  for (int j = 0; j < 8; j++) ones[j] = (short)0x3F80;
  const float4v initC = (float4v){-EXP_C2, -EXP_C2, -EXP_C2, -EXP_C2};

  for (int pass = 0; pass < 2; pass++) {
    const int q0 = (pass ? (31 - qp) : qp) * 64;
    const int qn = q0 + w * 16 + l15;
    const short8 qf0 = *(const short8*)&Qh[(size_t)qn * 64 + quad * 8];
    const short8 qf1 = *(const short8*)&Qh[(size_t)qn * 64 + 32 + quad * 8];

    float4v acc[4];
#pragma unroll
    for (int dt = 0; dt < 4; dt++) acc[dt] = (float4v){0.f, 0.f, 0.f, 0.f};
    float4v accL = (float4v){0.f, 0.f, 0.f, 0.f};

    // prologue: kb=0 tiles to regs
    short8 kv0 = *(const short8*)&Kh[(size_t)sr * 64 + gA];
    short8 kv1 = *(const short8*)&Kh[(size_t)sr * 64 + gB];
    short8 vv0 = *(const short8*)&Vh[(size_t)sr * 2048 + gA];
    short8 vv1 = *(const short8*)&Vh[(size_t)sr * 2048 + gB];

    int p = 0;
    for (int kb = 0; kb <= q0; kb += 64, p ^= 1) {
      const bool diag = (kb == q0);
      short* KsP = &Ks[p][0];
      short* VsP = &Vs[p][0];
      *(short8*)&KsP[stA] = kv0;
      *(short8*)&KsP[stB] = kv1;
      *(short8*)&VsP[stA] = vv0;
      *(short8*)&VsP[stB] = vv1;
      __syncthreads();

      // prefetch next k-block (redundant reload on last iter)
      const int kb2 = diag ? kb : kb + 64;
      kv0 = *(const short8*)&Kh[(size_t)(kb2 + sr) * 64 + gA];
      kv1 = *(const short8*)&Kh[(size_t)(kb2 + sr) * 64 + gB];
      vv0 = *(const short8*)&Vh[(size_t)sr * 2048 + kb2 + gA];
      vv1 = *(const short8*)&Vh[(size_t)sr * 2048 + kb2 + gB];

      // S^T = K Q^T ; exp arg = acc directly (Q pre-scaled, C-init = -C2)
#pragma unroll
      for (int kt = 0; kt < 4; kt++) {
        const int krb = (kt * 16 + l15) * 64;
        const short8 kf0 = *(const short8*)&KsP[krb + fc0];
        const short8 kf1 = *(const short8*)&KsP[krb + fc1];
        float4v s = __builtin_amdgcn_mfma_f32_16x16x32_bf16(kf0, qf0, initC, 0, 0, 0);
        s = __builtin_amdgcn_mfma_f32_16x16x32_bf16(kf1, qf1, s, 0, 0, 0);
        float p0 = __builtin_amdgcn_exp2f(s[0]);
        float p1 = __builtin_amdgcn_exp2f(s[1]);
        float p2 = __builtin_amdgcn_exp2f(s[2]);
        float p3 = __builtin_amdgcn_exp2f(s[3]);
        if (diag) {
          const int key = kb + kt * 16 + quad * 4;
          p0 = (key <= qn) ? p0 : 0.f;
          p1 = (key + 1 <= qn) ? p1 : 0.f;
          p2 = (key + 2 <= qn) ? p2 : 0.f;
          p3 = (key + 3 <= qn) ? p3 : 0.f;
        }
        uint2v pw;
        pw[0] = pack2bf(p0, p1);
        pw[1] = pack2bf(p2, p3);
        *(uint2v*)&PsW[pwr + (((2 * kt + (quad >> 1)) ^ fsw) << 3) +
                       ((quad & 1) << 2)] = pw;
      }
      __builtin_amdgcn_wave_barrier();

      // O^T += V^T P^T ; l += 1 P^T
      const short8 pf0 = *(const short8*)&PsW[pwr + fc0];
      const short8 pf1 = *(const short8*)&PsW[pwr + fc1];
#pragma unroll
      for (int dt = 0; dt < 4; dt++) {
        const int vrb = (dt * 16 + l15) * 64;
        const short8 vf0 = *(const short8*)&VsP[vrb + fc0];
        const short8 vf1 = *(const short8*)&VsP[vrb + fc1];
        acc[dt] = __builtin_amdgcn_mfma_f32_16x16x32_bf16(vf0, pf0, acc[dt], 0, 0, 0);
        acc[dt] = __builtin_amdgcn_mfma_f32_16x16x32_bf16(vf1, pf1, acc[dt], 0, 0, 0);
      }
      accL = __builtin_amdgcn_mfma_f32_16x16x32_bf16(ones, pf0, accL, 0, 0, 0);
      accL = __builtin_amdgcn_mfma_f32_16x16x32_bf16(ones, pf1, accL, 0, 0, 0);
    }

    const float inv = 1.0f / fmaxf(accL[0], 1e-30f);
#pragma unroll
    for (int dt = 0; dt < 4; dt++) {
      short4v o;
#pragma unroll
      for (int ri = 0; ri < 4; ri++) o[ri] = f2bf(acc[dt][ri] * inv);
      *(short4v*)&Qh[(size_t)qn * 64 + dt * 16 + quad * 4] = o;
    }
    if (pass == 0) __syncthreads();  // re-align barrier counts across waves
  }
}

extern "C" void kernel_launch(void* const* d_in, const int* in_sizes, int n_in,
                              void* d_out, int out_size, void* d_ws,
                              size_t ws_size, hipStream_t stream) {
  const float* x = (const float*)d_in[0];
  const float* wq = (const float*)d_in[1];
  const float* wk = (const float*)d_in[2];
  const float* wv = (const float*)d_in[3];
  const float* wo = (const float*)d_in[4];
  float* out = (float*)d_out;

  // d_out scratch (32 MB, dead until k4 overwrites it fully)
  short* xb = (short*)d_out;                 // bf16 x (16 MB)
  short* vtg = xb + (size_t)8192 * 1024;     // V^T (16 MB)

  // d_ws (bf16)
  short* wqb = (short*)d_ws;
  short* wkb = wqb + (size_t)1024 * 1024;
  short* wvb = wkb + (size_t)1024 * 1024;
  short* wob = wvb + (size_t)1024 * 1024;
  short* qws = wob + (size_t)1024 * 1024;    // [B,H,S,dk], O in-place
  short* kws = qws + (size_t)8192 * 1024;

  cvtAll<<<12288, 256, 0, stream>>>(x, wq, wk, wv, wo, xb, wqb, wkb, wvb, wob);
  gemm_bt<0><<<1536, 256, 0, stream>>>(
      xb, wqb, wkb, wvb, qws, kws, vtg, nullptr);
  attn4<<<dim3(64, 16), 256, 0, stream>>>(qws, kws, vtg);
  gemm_bt<1><<<512, 256, 0, stream>>>(
      qws, wob, nullptr, nullptr, nullptr, nullptr, nullptr, out);
}

// Round 4
// 259.050 us; speedup vs baseline: 2.4236x; 2.4236x over previous
//
#include <hip/hip_runtime.h>
#include <stdint.h>

// MHSA: B=4, S=2048, D=1024, H=16, dk=64. fp32 in/out, bf16 MFMA compute.
//
// Pipeline:
//  k0: cvtAll    fp32 -> bf16 for x + all 4 weights (single launch).
//  k1: gemm<0>   Q,K projection (grid 1024); Q pre-scaled by 0.125*log2(e).
//  k2: gemm<2>   V projection (grid 512); writes V^T [B,H,dk,S] directly.
//               R11: split from one fused QKV kernel — carrying both
//               epilogue forms in one kernel inflated VGPR 76->104
//               (occupancy 27->20.5%, 74.9->81us). R10's launch_bounds(256,6)
//               fix spilled acc to scratch (VGPR 40, 1.1GB WRITE, 364us) —
//               never bound below the 64-VGPR accumulator floor.
//               R9 XCD swizzle retained: o%8 = XCD owns 8 m-blocks (2MB
//               A-slice L2-resident); FETCH 137->49MB verified.
//  k3: attn4    S^T = K Q^T flash attention; C-init = -4*log2(e);
//               v_perm bf16 pack; XOR-swizzled LDS; double-buffered K/V,
//               one barrier/iter; rowsum via ones-MFMA; O over Q in-place.
//               R8: grid (bh, qp): id%8 = bh%8 => per-head XCD/L2 locality.
//  k4: gemm<1>  output projection, fp32 out (grid 512).

typedef __attribute__((ext_vector_type(8))) short short8;
typedef __attribute__((ext_vector_type(4))) short short4v;
typedef __attribute__((ext_vector_type(4))) float float4v;
typedef __attribute__((ext_vector_type(2))) unsigned int uint2v;

#define QSCALE 0.18033688011112042f  // 0.125 * log2(e), folded into Q
#define EXP_C2 5.770780163555852f    // 4 * log2(e), folded into MFMA C-init

__device__ inline short f2bf(float f) {
  union { float f; uint32_t u; } v; v.f = f;
  uint32_t r = (v.u + 0x7fffu + ((v.u >> 16) & 1)) >> 16;
  return (short)(uint16_t)r;
}

// pack 2 f32 -> 2 bf16 (truncating), a -> low short, b -> high short
__device__ inline unsigned int pack2bf(float a, float b) {
  union { float f; unsigned int u; } ua, ub;
  ua.f = a; ub.f = b;
  return __builtin_amdgcn_perm(ub.u, ua.u, 0x07060302u);
}

__device__ inline void async_copy16(const void* g, void* l) {
  __builtin_amdgcn_global_load_lds(
      (const __attribute__((address_space(1))) void*)g,
      (__attribute__((address_space(3))) void*)l, 16, 0, 0);
}

// ---------------------------------------------------------------------------
// fp32 -> bf16: x (8192 blocks) + 4 weights (1024 blocks each) in one launch.
// ---------------------------------------------------------------------------
__global__ __launch_bounds__(256) void cvtAll(
    const float* __restrict__ x, const float* __restrict__ wq,
    const float* __restrict__ wk, const float* __restrict__ wv,
    const float* __restrict__ wo,
    short* __restrict__ xb, short* __restrict__ wqb, short* __restrict__ wkb,
    short* __restrict__ wvb, short* __restrict__ wob) {
  const int b = blockIdx.x;
  const float* s; short* d; int base;
  if (b < 8192) { s = x; d = xb; base = b; }
  else {
    const int wi = (b - 8192) >> 10; base = (b - 8192) & 1023;
    s = (wi == 0) ? wq : (wi == 1) ? wk : (wi == 2) ? wv : wo;
    d = (wi == 0) ? wqb : (wi == 1) ? wkb : (wi == 2) ? wvb : wob;
  }
  const size_t i = (size_t)base * 256 + threadIdx.x;
  const float4v v = *(const float4v*)(s + 4 * i);
  short4v o;
  o[0] = f2bf(v[0]); o[1] = f2bf(v[1]);
  o[2] = f2bf(v[2]); o[3] = f2bf(v[3]);
  *(short4v*)(d + 4 * i) = o;
}

// ---------------------------------------------------------------------------
// GEMM: Y[8192][1024] = A[8192][1024] @ W^T bf16.
// MODE 0: grid 1024; Q (scaled) and K via decoded zz; Y bf16 [B,H,S,dk].
// MODE 2: grid 512;  V; Y = V^T bf16 [B,H,dk,S] (transposed epilogue only).
// MODE 1: grid 512;  A read through [B,H,S,dk] map; Y fp32 row-major.
// XCD swizzle: o%8 = XCD owns m-blocks [8k,8k+8); (n[,zz]) walked per XCD.
// ---------------------------------------------------------------------------
template <int MODE>
__global__ __launch_bounds__(256) void gemm_bt(
    const short* __restrict__ A,
    const short* __restrict__ W0, const short* __restrict__ W1,
    short* __restrict__ Yb0, short* __restrict__ Yb1,
    float* __restrict__ Yf) {
  constexpr int Kd = 1024;
  __shared__ __align__(16) short As[128 * 32];
  __shared__ __align__(16) short Bs[128 * 32];

  const int t = threadIdx.x;
  const int w = t >> 6, l = t & 63, l15 = l & 15, quad = l >> 4;
  const int wm = w >> 1, wn = w & 1;

  int mblk, nblk, zz = 0;
  {
    const int o = blockIdx.x;
    const int xcd = o & 7, slot = o >> 3;
    mblk = (xcd << 3) | (slot & 7);
    const int c = slot >> 3;
    if (MODE == 0) { nblk = c & 7; zz = c >> 3; }   // c in [0,16)
    else nblk = c;                                   // c in [0,8)
  }
  const int m0 = mblk * 128, n0 = nblk * 128;

  const short* W = W0;
  short* Yb = Yb0;
  float sc = 1.0f;
  if (MODE == 0) {
    if (zz == 0) sc = QSCALE;
    else { W = W1; Yb = Yb1; }
  }

  float4v acc[4][4];
#pragma unroll
  for (int i = 0; i < 4; i++)
#pragma unroll
    for (int j = 0; j < 4; j++) acc[i][j] = (float4v){0.f, 0.f, 0.f, 0.f};

  const int r4 = t >> 2, c48 = (t & 3) * 8;
  const short* Wbase = W + (n0 + r4) * Kd + c48;
  short* AsW = &As[w * 512];
  short* BsW = &Bs[w * 512];
  const int i0 = m0 + r4;
  const int i1 = m0 + 64 + r4;

  for (int k0 = 0; k0 < Kd; k0 += 32) {
    if (MODE != 1) {
      async_copy16(A + (size_t)i0 * Kd + k0 + c48, AsW);
      async_copy16(A + (size_t)i1 * Kd + k0 + c48, AsW + 2048);
    } else {
      const int k = k0 + c48, h = k >> 6, dd = k & 63;
      async_copy16(A + ((((size_t)(i0 >> 11) * 16 + h) * 2048 + (i0 & 2047)) * 64 + dd), AsW);
      async_copy16(A + ((((size_t)(i1 >> 11) * 16 + h) * 2048 + (i1 & 2047)) * 64 + dd), AsW + 2048);
    }
    async_copy16(Wbase + k0, BsW);
    async_copy16(Wbase + 64 * Kd + k0, BsW + 2048);
    __syncthreads();
    short8 af[4], bf[4];
#pragma unroll
    for (int mi = 0; mi < 4; mi++)
      af[mi] = *(const short8*)&As[(wm * 64 + mi * 16 + l15) * 32 + quad * 8];
#pragma unroll
    for (int ni = 0; ni < 4; ni++)
      bf[ni] = *(const short8*)&Bs[(wn * 64 + ni * 16 + l15) * 32 + quad * 8];
#pragma unroll
    for (int mi = 0; mi < 4; mi++)
#pragma unroll
      for (int ni = 0; ni < 4; ni++)
        acc[mi][ni] = __builtin_amdgcn_mfma_f32_16x16x32_bf16(
            af[mi], bf[ni], acc[mi][ni], 0, 0, 0);
    __syncthreads();
  }

#pragma unroll
  for (int mi = 0; mi < 4; mi++) {
    const int ib = m0 + wm * 64 + mi * 16 + quad * 4;
#pragma unroll
    for (int ni = 0; ni < 4; ni++) {
      const int j = n0 + wn * 64 + ni * 16 + l15;
      if (MODE == 2) {
        // V^T store: [B,H,dk,S]; rows ib..ib+3 are consecutive s -> short4.
        short4v o;
#pragma unroll
        for (int r = 0; r < 4; r++) o[r] = f2bf(acc[mi][ni][r]);
        *(short4v*)&Yb[(((size_t)(ib >> 11) * 16 + (j >> 6)) * 64 + (j & 63)) * 2048 +
                       (ib & 2047)] = o;
      } else {
#pragma unroll
        for (int r = 0; r < 4; r++) {
          const int i = ib + r;
          if (MODE == 0) {
            Yb[((((size_t)(i >> 11) * 16 + (j >> 6)) * 2048 + (i & 2047)) * 64 + (j & 63))] =
                f2bf(acc[mi][ni][r] * sc);
          } else {
            Yf[(size_t)i * 1024 + j] = acc[mi][ni][r];
          }
        }
      }
    }
  }
}

// ---------------------------------------------------------------------------
// Flash attention v4 + XCD swizzle. grid (64 bh, 16 qp), 256 thr = 4 waves.
// Paired q-tiles (qp, 31-qp). XOR-swizzled LDS rows of 64 shorts.
// Double-buffered K/V, one __syncthreads per 64-key iter.
// ---------------------------------------------------------------------------
__global__ __launch_bounds__(256) void attn4(
    short* __restrict__ Q,          // [B,H,S,dk] in, O out
    const short* __restrict__ K,    // [B,H,S,dk]
    const short* __restrict__ VT) { // [B,H,dk,S]
  __shared__ __align__(16) short Ks[2][64 * 64];
  __shared__ __align__(16) short Vs[2][64 * 64];
  __shared__ __align__(16) short Ps[4][16 * 64];

  const int t = threadIdx.x;
  const int w = t >> 6, l = t & 63, l15 = l & 15, quad = l >> 4;
  const int bh = blockIdx.x;   // R8: bh on x => id%8 = bh%8 => per-head XCD
  const int qp = blockIdx.y;   // q-pair index 0..15
  short* Qh = Q + (size_t)bh * 2048 * 64;
  const short* Kh = K + (size_t)bh * 2048 * 64;
  const short* Vh = VT + (size_t)bh * 64 * 2048;

  // staging: thread t covers row sr (0..63), short-chunks 2c0, 2c0+1
  const int sr = t >> 2, c0 = t & 3;
  const int ssw = sr & 7;
  const int stA = sr * 64 + (((2 * c0) ^ ssw) << 3);
  const int stB = sr * 64 + (((2 * c0 + 1) ^ ssw) << 3);
  const int gA = c0 * 16, gB = c0 * 16 + 8;

  // fragment chunk swizzle key
  const int fsw = l15 & 7;
  const int fc0 = (quad ^ fsw) << 3;
  const int fc1 = ((4 + quad) ^ fsw) << 3;
  short* PsW = &Ps[w][0];
  const int pwr = l15 * 64;

  short8 ones;
#pragma unroll
  for (int j = 0; j < 8; j++) ones[j] = (short)0x3F80;
  const float4v initC = (float4v){-EXP_C2, -EXP_C2, -EXP_C2, -EXP_C2};

  for (int pass = 0; pass < 2; pass++) {
    const int q0 = (pass ? (31 - qp) : qp) * 64;
    const int qn = q0 + w * 16 + l15;
    const short8 qf0 = *(const short8*)&Qh[(size_t)qn * 64 + quad * 8];
    const short8 qf1 = *(const short8*)&Qh[(size_t)qn * 64 + 32 + quad * 8];

    float4v acc[4];
#pragma unroll
    for (int dt = 0; dt < 4; dt++) acc[dt] = (float4v){0.f, 0.f, 0.f, 0.f};
    float4v accL = (float4v){0.f, 0.f, 0.f, 0.f};

    // prologue: kb=0 tiles to regs
    short8 kv0 = *(const short8*)&Kh[(size_t)sr * 64 + gA];
    short8 kv1 = *(const short8*)&Kh[(size_t)sr * 64 + gB];
    short8 vv0 = *(const short8*)&Vh[(size_t)sr * 2048 + gA];
    short8 vv1 = *(const short8*)&Vh[(size_t)sr * 2048 + gB];

    int p = 0;
    for (int kb = 0; kb <= q0; kb += 64, p ^= 1) {
      const bool diag = (kb == q0);
      short* KsP = &Ks[p][0];
      short* VsP = &Vs[p][0];
      *(short8*)&KsP[stA] = kv0;
      *(short8*)&KsP[stB] = kv1;
      *(short8*)&VsP[stA] = vv0;
      *(short8*)&VsP[stB] = vv1;
      __syncthreads();

      // prefetch next k-block (redundant reload on last iter)
      const int kb2 = diag ? kb : kb + 64;
      kv0 = *(const short8*)&Kh[(size_t)(kb2 + sr) * 64 + gA];
      kv1 = *(const short8*)&Kh[(size_t)(kb2 + sr) * 64 + gB];
      vv0 = *(const short8*)&Vh[(size_t)sr * 2048 + kb2 + gA];
      vv1 = *(const short8*)&Vh[(size_t)sr * 2048 + kb2 + gB];

      // S^T = K Q^T ; exp arg = acc directly (Q pre-scaled, C-init = -C2)
#pragma unroll
      for (int kt = 0; kt < 4; kt++) {
        const int krb = (kt * 16 + l15) * 64;
        const short8 kf0 = *(const short8*)&KsP[krb + fc0];
        const short8 kf1 = *(const short8*)&KsP[krb + fc1];
        float4v s = __builtin_amdgcn_mfma_f32_16x16x32_bf16(kf0, qf0, initC, 0, 0, 0);
        s = __builtin_amdgcn_mfma_f32_16x16x32_bf16(kf1, qf1, s, 0, 0, 0);
        float p0 = __builtin_amdgcn_exp2f(s[0]);
        float p1 = __builtin_amdgcn_exp2f(s[1]);
        float p2 = __builtin_amdgcn_exp2f(s[2]);
        float p3 = __builtin_amdgcn_exp2f(s[3]);
        if (diag) {
          const int key = kb + kt * 16 + quad * 4;
          p0 = (key <= qn) ? p0 : 0.f;
          p1 = (key + 1 <= qn) ? p1 : 0.f;
          p2 = (key + 2 <= qn) ? p2 : 0.f;
          p3 = (key + 3 <= qn) ? p3 : 0.f;
        }
        uint2v pw;
        pw[0] = pack2bf(p0, p1);
        pw[1] = pack2bf(p2, p3);
        *(uint2v*)&PsW[pwr + (((2 * kt + (quad >> 1)) ^ fsw) << 3) +
                       ((quad & 1) << 2)] = pw;
      }
      __builtin_amdgcn_wave_barrier();

      // O^T += V^T P^T ; l += 1 P^T
      const short8 pf0 = *(const short8*)&PsW[pwr + fc0];
      const short8 pf1 = *(const short8*)&PsW[pwr + fc1];
#pragma unroll
      for (int dt = 0; dt < 4; dt++) {
        const int vrb = (dt * 16 + l15) * 64;
        const short8 vf0 = *(const short8*)&VsP[vrb + fc0];
        const short8 vf1 = *(const short8*)&VsP[vrb + fc1];
        acc[dt] = __builtin_amdgcn_mfma_f32_16x16x32_bf16(vf0, pf0, acc[dt], 0, 0, 0);
        acc[dt] = __builtin_amdgcn_mfma_f32_16x16x32_bf16(vf1, pf1, acc[dt], 0, 0, 0);
      }
      accL = __builtin_amdgcn_mfma_f32_16x16x32_bf16(ones, pf0, accL, 0, 0, 0);
      accL = __builtin_amdgcn_mfma_f32_16x16x32_bf16(ones, pf1, accL, 0, 0, 0);
    }

    const float inv = 1.0f / fmaxf(accL[0], 1e-30f);
#pragma unroll
    for (int dt = 0; dt < 4; dt++) {
      short4v o;
#pragma unroll
      for (int ri = 0; ri < 4; ri++) o[ri] = f2bf(acc[dt][ri] * inv);
      *(short4v*)&Qh[(size_t)qn * 64 + dt * 16 + quad * 4] = o;
    }
    if (pass == 0) __syncthreads();  // re-align barrier counts across waves
  }
}

extern "C" void kernel_launch(void* const* d_in, const int* in_sizes, int n_in,
                              void* d_out, int out_size, void* d_ws,
                              size_t ws_size, hipStream_t stream) {
  const float* x = (const float*)d_in[0];
  const float* wq = (const float*)d_in[1];
  const float* wk = (const float*)d_in[2];
  const float* wv = (const float*)d_in[3];
  const float* wo = (const float*)d_in[4];
  float* out = (float*)d_out;

  // d_out scratch (32 MB, dead until k4 overwrites it fully)
  short* xb = (short*)d_out;                 // bf16 x (16 MB)
  short* vtg = xb + (size_t)8192 * 1024;     // V^T (16 MB)

  // d_ws (bf16)
  short* wqb = (short*)d_ws;
  short* wkb = wqb + (size_t)1024 * 1024;
  short* wvb = wkb + (size_t)1024 * 1024;
  short* wob = wvb + (size_t)1024 * 1024;
  short* qws = wob + (size_t)1024 * 1024;    // [B,H,S,dk], O in-place
  short* kws = qws + (size_t)8192 * 1024;

  cvtAll<<<12288, 256, 0, stream>>>(x, wq, wk, wv, wo, xb, wqb, wkb, wvb, wob);
  gemm_bt<0><<<1024, 256, 0, stream>>>(
      xb, wqb, wkb, qws, kws, nullptr);
  gemm_bt<2><<<512, 256, 0, stream>>>(
      xb, wvb, nullptr, vtg, nullptr, nullptr);
  attn4<<<dim3(64, 16), 256, 0, stream>>>(qws, kws, vtg);
  gemm_bt<1><<<512, 256, 0, stream>>>(
      qws, wob, nullptr, nullptr, nullptr, out);
}

// Round 6
// 252.185 us; speedup vs baseline: 2.4896x; 1.0272x over previous
//
#include <hip/hip_runtime.h>
#include <stdint.h>

// MHSA: B=4, S=2048, D=1024, H=16, dk=64. fp32 in/out, bf16 MFMA compute.
//
// Pipeline:
//  k0: cvtAll    fp32 -> bf16 for x + all 4 weights (single launch).
//  k1: gemm<0>   Q,K projection (grid 1024); Q pre-scaled by 0.125*log2(e).
//  k2: gemm<2>   V projection (grid 512); writes V^T [B,H,dk,S] directly.
//               R11: split from fused QKV (dual epilogue inflated VGPR
//               76->104, occ 27->20.5%). R10 lesson: never launch_bounds
//               below the 64-VGPR accumulator floor (spilled acc, 364us).
//               R9 XCD swizzle retained (FETCH 137->49MB verified).
//  k3: attn4    R13: reverted to R11-proven two-pass body (R12's 32q/wave
//               rewrite failed absmax 0.239 with no locatable index bug —
//               reverted rather than fix-forward). Added s_setprio(1/0)
//               around QK+PV MFMA clusters (T5: attn +4-7%, zero
//               correctness surface).
//               R8: grid (bh, qp): id%8 = bh%8 => per-head XCD/L2 locality.
//  k4: gemm<1>  output projection, fp32 out (grid 512).

typedef __attribute__((ext_vector_type(8))) short short8;
typedef __attribute__((ext_vector_type(4))) short short4v;
typedef __attribute__((ext_vector_type(4))) float float4v;
typedef __attribute__((ext_vector_type(2))) unsigned int uint2v;

#define QSCALE 0.18033688011112042f  // 0.125 * log2(e), folded into Q
#define EXP_C2 5.770780163555852f    // 4 * log2(e), folded into MFMA C-init

__device__ inline short f2bf(float f) {
  union { float f; uint32_t u; } v; v.f = f;
  uint32_t r = (v.u + 0x7fffu + ((v.u >> 16) & 1)) >> 16;
  return (short)(uint16_t)r;
}

// pack 2 f32 -> 2 bf16 (truncating), a -> low short, b -> high short
__device__ inline unsigned int pack2bf(float a, float b) {
  union { float f; unsigned int u; } ua, ub;
  ua.f = a; ub.f = b;
  return __builtin_amdgcn_perm(ub.u, ua.u, 0x07060302u);
}

__device__ inline void async_copy16(const void* g, void* l) {
  __builtin_amdgcn_global_load_lds(
      (const __attribute__((address_space(1))) void*)g,
      (__attribute__((address_space(3))) void*)l, 16, 0, 0);
}

// ---------------------------------------------------------------------------
// fp32 -> bf16: x (8192 blocks) + 4 weights (1024 blocks each) in one launch.
// ---------------------------------------------------------------------------
__global__ __launch_bounds__(256) void cvtAll(
    const float* __restrict__ x, const float* __restrict__ wq,
    const float* __restrict__ wk, const float* __restrict__ wv,
    const float* __restrict__ wo,
    short* __restrict__ xb, short* __restrict__ wqb, short* __restrict__ wkb,
    short* __restrict__ wvb, short* __restrict__ wob) {
  const int b = blockIdx.x;
  const float* s; short* d; int base;
  if (b < 8192) { s = x; d = xb; base = b; }
  else {
    const int wi = (b - 8192) >> 10; base = (b - 8192) & 1023;
    s = (wi == 0) ? wq : (wi == 1) ? wk : (wi == 2) ? wv : wo;
    d = (wi == 0) ? wqb : (wi == 1) ? wkb : (wi == 2) ? wvb : wob;
  }
  const size_t i = (size_t)base * 256 + threadIdx.x;
  const float4v v = *(const float4v*)(s + 4 * i);
  short4v o;
  o[0] = f2bf(v[0]); o[1] = f2bf(v[1]);
  o[2] = f2bf(v[2]); o[3] = f2bf(v[3]);
  *(short4v*)(d + 4 * i) = o;
}

// ---------------------------------------------------------------------------
// GEMM: Y[8192][1024] = A[8192][1024] @ W^T bf16.
// MODE 0: grid 1024; Q (scaled) and K via decoded zz; Y bf16 [B,H,S,dk].
// MODE 2: grid 512;  V; Y = V^T bf16 [B,H,dk,S] (transposed epilogue only).
// MODE 1: grid 512;  A read through [B,H,S,dk] map; Y fp32 row-major.
// XCD swizzle: o%8 = XCD owns m-blocks [8k,8k+8); (n[,zz]) walked per XCD.
// ---------------------------------------------------------------------------
template <int MODE>
__global__ __launch_bounds__(256) void gemm_bt(
    const short* __restrict__ A,
    const short* __restrict__ W0, const short* __restrict__ W1,
    short* __restrict__ Yb0, short* __restrict__ Yb1,
    float* __restrict__ Yf) {
  constexpr int Kd = 1024;
  __shared__ __align__(16) short As[128 * 32];
  __shared__ __align__(16) short Bs[128 * 32];

  const int t = threadIdx.x;
  const int w = t >> 6, l = t & 63, l15 = l & 15, quad = l >> 4;
  const int wm = w >> 1, wn = w & 1;

  int mblk, nblk, zz = 0;
  {
    const int o = blockIdx.x;
    const int xcd = o & 7, slot = o >> 3;
    mblk = (xcd << 3) | (slot & 7);
    const int c = slot >> 3;
    if (MODE == 0) { nblk = c & 7; zz = c >> 3; }   // c in [0,16)
    else nblk = c;                                   // c in [0,8)
  }
  const int m0 = mblk * 128, n0 = nblk * 128;

  const short* W = W0;
  short* Yb = Yb0;
  float sc = 1.0f;
  if (MODE == 0) {
    if (zz == 0) sc = QSCALE;
    else { W = W1; Yb = Yb1; }
  }

  float4v acc[4][4];
#pragma unroll
  for (int i = 0; i < 4; i++)
#pragma unroll
    for (int j = 0; j < 4; j++) acc[i][j] = (float4v){0.f, 0.f, 0.f, 0.f};

  const int r4 = t >> 2, c48 = (t & 3) * 8;
  const short* Wbase = W + (n0 + r4) * Kd + c48;
  short* AsW = &As[w * 512];
  short* BsW = &Bs[w * 512];
  const int i0 = m0 + r4;
  const int i1 = m0 + 64 + r4;

  for (int k0 = 0; k0 < Kd; k0 += 32) {
    if (MODE != 1) {
      async_copy16(A + (size_t)i0 * Kd + k0 + c48, AsW);
      async_copy16(A + (size_t)i1 * Kd + k0 + c48, AsW + 2048);
    } else {
      const int k = k0 + c48, h = k >> 6, dd = k & 63;
      async_copy16(A + ((((size_t)(i0 >> 11) * 16 + h) * 2048 + (i0 & 2047)) * 64 + dd), AsW);
      async_copy16(A + ((((size_t)(i1 >> 11) * 16 + h) * 2048 + (i1 & 2047)) * 64 + dd), AsW + 2048);
    }
    async_copy16(Wbase + k0, BsW);
    async_copy16(Wbase + 64 * Kd + k0, BsW + 2048);
    __syncthreads();
    short8 af[4], bf[4];
#pragma unroll
    for (int mi = 0; mi < 4; mi++)
      af[mi] = *(const short8*)&As[(wm * 64 + mi * 16 + l15) * 32 + quad * 8];
#pragma unroll
    for (int ni = 0; ni < 4; ni++)
      bf[ni] = *(const short8*)&Bs[(wn * 64 + ni * 16 + l15) * 32 + quad * 8];
#pragma unroll
    for (int mi = 0; mi < 4; mi++)
#pragma unroll
      for (int ni = 0; ni < 4; ni++)
        acc[mi][ni] = __builtin_amdgcn_mfma_f32_16x16x32_bf16(
            af[mi], bf[ni], acc[mi][ni], 0, 0, 0);
    __syncthreads();
  }

#pragma unroll
  for (int mi = 0; mi < 4; mi++) {
    const int ib = m0 + wm * 64 + mi * 16 + quad * 4;
#pragma unroll
    for (int ni = 0; ni < 4; ni++) {
      const int j = n0 + wn * 64 + ni * 16 + l15;
      if (MODE == 2) {
        // V^T store: [B,H,dk,S]; rows ib..ib+3 are consecutive s -> short4.
        short4v o;
#pragma unroll
        for (int r = 0; r < 4; r++) o[r] = f2bf(acc[mi][ni][r]);
        *(short4v*)&Yb[(((size_t)(ib >> 11) * 16 + (j >> 6)) * 64 + (j & 63)) * 2048 +
                       (ib & 2047)] = o;
      } else {
#pragma unroll
        for (int r = 0; r < 4; r++) {
          const int i = ib + r;
          if (MODE == 0) {
            Yb[((((size_t)(i >> 11) * 16 + (j >> 6)) * 2048 + (i & 2047)) * 64 + (j & 63))] =
                f2bf(acc[mi][ni][r] * sc);
          } else {
            Yf[(size_t)i * 1024 + j] = acc[mi][ni][r];
          }
        }
      }
    }
  }
}

// ---------------------------------------------------------------------------
// Flash attention v4 + XCD swizzle. grid (64 bh, 16 qp), 256 thr = 4 waves.
// Paired q-tiles (qp, 31-qp). XOR-swizzled LDS rows of 64 shorts.
// Double-buffered K/V, one __syncthreads per 64-key iter.
// R13: s_setprio(1) around QK and PV MFMA clusters (T5).
// ---------------------------------------------------------------------------
__global__ __launch_bounds__(256) void attn4(
    short* __restrict__ Q,          // [B,H,S,dk] in, O out
    const short* __restrict__ K,    // [B,H,S,dk]
    const short* __restrict__ VT) { // [B,H,dk,S]
  __shared__ __align__(16) short Ks[2][64 * 64];
  __shared__ __align__(16) short Vs[2][64 * 64];
  __shared__ __align__(16) short Ps[4][16 * 64];

  const int t = threadIdx.x;
  const int w = t >> 6, l = t & 63, l15 = l & 15, quad = l >> 4;
  const int bh = blockIdx.x;   // R8: bh on x => id%8 = bh%8 => per-head XCD
  const int qp = blockIdx.y;   // q-pair index 0..15
  short* Qh = Q + (size_t)bh * 2048 * 64;
  const short* Kh = K + (size_t)bh * 2048 * 64;
  const short* Vh = VT + (size_t)bh * 64 * 2048;

  // staging: thread t covers row sr (0..63), short-chunks 2c0, 2c0+1
  const int sr = t >> 2, c0 = t & 3;
  const int ssw = sr & 7;
  const int stA = sr * 64 + (((2 * c0) ^ ssw) << 3);
  const int stB = sr * 64 + (((2 * c0 + 1) ^ ssw) << 3);
  const int gA = c0 * 16, gB = c0 * 16 + 8;

  // fragment chunk swizzle key
  const int fsw = l15 & 7;
  const int fc0 = (quad ^ fsw) << 3;
  const int fc1 = ((4 + quad) ^ fsw) << 3;
  short* PsW = &Ps[w][0];
  const int pwr = l15 * 64;

  short8 ones;
#pragma unroll
  for (int j = 0; j < 8; j++) ones[j] = (short)0x3F80;
  const float4v initC = (float4v){-EXP_C2, -EXP_C2, -EXP_C2, -EXP_C2};

  for (int pass = 0; pass < 2; pass++) {
    const int q0 = (pass ? (31 - qp) : qp) * 64;
    const int qn = q0 + w * 16 + l15;
    const short8 qf0 = *(const short8*)&Qh[(size_t)qn * 64 + quad * 8];
    const short8 qf1 = *(const short8*)&Qh[(size_t)qn * 64 + 32 + quad * 8];

    float4v acc[4];
#pragma unroll
    for (int dt = 0; dt < 4; dt++) acc[dt] = (float4v){0.f, 0.f, 0.f, 0.f};
    float4v accL = (float4v){0.f, 0.f, 0.f, 0.f};

    // prologue: kb=0 tiles to regs
    short8 kv0 = *(const short8*)&Kh[(size_t)sr * 64 + gA];
    short8 kv1 = *(const short8*)&Kh[(size_t)sr * 64 + gB];
    short8 vv0 = *(const short8*)&Vh[(size_t)sr * 2048 + gA];
    short8 vv1 = *(const short8*)&Vh[(size_t)sr * 2048 + gB];

    int p = 0;
    for (int kb = 0; kb <= q0; kb += 64, p ^= 1) {
      const bool diag = (kb == q0);
      short* KsP = &Ks[p][0];
      short* VsP = &Vs[p][0];
      *(short8*)&KsP[stA] = kv0;
      *(short8*)&KsP[stB] = kv1;
      *(short8*)&VsP[stA] = vv0;
      *(short8*)&VsP[stB] = vv1;
      __syncthreads();

      // prefetch next k-block (redundant reload on last iter)
      const int kb2 = diag ? kb : kb + 64;
      kv0 = *(const short8*)&Kh[(size_t)(kb2 + sr) * 64 + gA];
      kv1 = *(const short8*)&Kh[(size_t)(kb2 + sr) * 64 + gB];
      vv0 = *(const short8*)&Vh[(size_t)sr * 2048 + kb2 + gA];
      vv1 = *(const short8*)&Vh[(size_t)sr * 2048 + kb2 + gB];

      // S^T = K Q^T ; exp arg = acc directly (Q pre-scaled, C-init = -C2)
#pragma unroll
      for (int kt = 0; kt < 4; kt++) {
        const int krb = (kt * 16 + l15) * 64;
        const short8 kf0 = *(const short8*)&KsP[krb + fc0];
        const short8 kf1 = *(const short8*)&KsP[krb + fc1];
        __builtin_amdgcn_s_setprio(1);
        float4v s = __builtin_amdgcn_mfma_f32_16x16x32_bf16(kf0, qf0, initC, 0, 0, 0);
        s = __builtin_amdgcn_mfma_f32_16x16x32_bf16(kf1, qf1, s, 0, 0, 0);
        __builtin_amdgcn_s_setprio(0);
        float p0 = __builtin_amdgcn_exp2f(s[0]);
        float p1 = __builtin_amdgcn_exp2f(s[1]);
        float p2 = __builtin_amdgcn_exp2f(s[2]);
        float p3 = __builtin_amdgcn_exp2f(s[3]);
        if (diag) {
          const int key = kb + kt * 16 + quad * 4;
          p0 = (key <= qn) ? p0 : 0.f;
          p1 = (key + 1 <= qn) ? p1 : 0.f;
          p2 = (key + 2 <= qn) ? p2 : 0.f;
          p3 = (key + 3 <= qn) ? p3 : 0.f;
        }
        uint2v pw;
        pw[0] = pack2bf(p0, p1);
        pw[1] = pack2bf(p2, p3);
        *(uint2v*)&PsW[pwr + (((2 * kt + (quad >> 1)) ^ fsw) << 3) +
                       ((quad & 1) << 2)] = pw;
      }
      __builtin_amdgcn_wave_barrier();

      // O^T += V^T P^T ; l += 1 P^T
      const short8 pf0 = *(const short8*)&PsW[pwr + fc0];
      const short8 pf1 = *(const short8*)&PsW[pwr + fc1];
      __builtin_amdgcn_s_setprio(1);
#pragma unroll
      for (int dt = 0; dt < 4; dt++) {
        const int vrb = (dt * 16 + l15) * 64;
        const short8 vf0 = *(const short8*)&VsP[vrb + fc0];
        const short8 vf1 = *(const short8*)&VsP[vrb + fc1];
        acc[dt] = __builtin_amdgcn_mfma_f32_16x16x32_bf16(vf0, pf0, acc[dt], 0, 0, 0);
        acc[dt] = __builtin_amdgcn_mfma_f32_16x16x32_bf16(vf1, pf1, acc[dt], 0, 0, 0);
      }
      accL = __builtin_amdgcn_mfma_f32_16x16x32_bf16(ones, pf0, accL, 0, 0, 0);
      accL = __builtin_amdgcn_mfma_f32_16x16x32_bf16(ones, pf1, accL, 0, 0, 0);
      __builtin_amdgcn_s_setprio(0);
    }

    const float inv = 1.0f / fmaxf(accL[0], 1e-30f);
#pragma unroll
    for (int dt = 0; dt < 4; dt++) {
      short4v o;
#pragma unroll
      for (int ri = 0; ri < 4; ri++) o[ri] = f2bf(acc[dt][ri] * inv);
      *(short4v*)&Qh[(size_t)qn * 64 + dt * 16 + quad * 4] = o;
    }
    if (pass == 0) __syncthreads();  // re-align barrier counts across waves
  }
}

extern "C" void kernel_launch(void* const* d_in, const int* in_sizes, int n_in,
                              void* d_out, int out_size, void* d_ws,
                              size_t ws_size, hipStream_t stream) {
  const float* x = (const float*)d_in[0];
  const float* wq = (const float*)d_in[1];
  const float* wk = (const float*)d_in[2];
  const float* wv = (const float*)d_in[3];
  const float* wo = (const float*)d_in[4];
  float* out = (float*)d_out;

  // d_out scratch (32 MB, dead until k4 overwrites it fully)
  short* xb = (short*)d_out;                 // bf16 x (16 MB)
  short* vtg = xb + (size_t)8192 * 1024;     // V^T (16 MB)

  // d_ws (bf16)
  short* wqb = (short*)d_ws;
  short* wkb = wqb + (size_t)1024 * 1024;
  short* wvb = wkb + (size_t)1024 * 1024;
  short* wob = wvb + (size_t)1024 * 1024;
  short* qws = wob + (size_t)1024 * 1024;    // [B,H,S,dk], O in-place
  short* kws = qws + (size_t)8192 * 1024;

  cvtAll<<<12288, 256, 0, stream>>>(x, wq, wk, wv, wo, xb, wqb, wkb, wvb, wob);
  gemm_bt<0><<<1024, 256, 0, stream>>>(
      xb, wqb, wkb, qws, kws, nullptr);
  gemm_bt<2><<<512, 256, 0, stream>>>(
      xb, wvb, nullptr, vtg, nullptr, nullptr);
  attn4<<<dim3(64, 16), 256, 0, stream>>>(qws, kws, vtg);
  gemm_bt<1><<<512, 256, 0, stream>>>(
      qws, wob, nullptr, nullptr, nullptr, out);
}